// Round 6
// baseline (184.755 us; speedup 1.0000x reference)
//
#include <hip/hip_runtime.h>
#include <math.h>

// Forward kinematics chain: B=32768 batches, J=20 joints.
// out = concat(TrackingSE3 (B,10,4,4), RevSE3 (B,20,4,4), PriSE3 (B,20,4,4)) fp32.
//
// v4: DPP-based scan. v3's 72 ds_bpermute/lane-group (~16us/CU of LDS-pipe
// serialization) are replaced by row_shr DPP ops on the VALU:
//  - lane l of a 16-lane row owns joints {2l, 2l+1} (10 active lanes/row,
//    4 batches per wave64),
//  - pair-product Q_l = S_2l @ S_2l+1, Kogge-Stone over 10 lanes (d=1,2,4,8)
//    entirely via row_shr:d DPP (intra-row, VALU, no LDS traffic),
//  - exclusive prefix E = row_shr:1(V), E_0 = I; reconstruct
//    rev0=E@rs0, T0=E@S0 (=pri0), rev1=T0@rs1, pri1=V, trk=T0@Ttrack.
// Staging + per-wave coalesced nontemporal copy (wave owns 4 consecutive
// batches -> contiguous global spans; no __syncthreads in hot path).

constexpr int NJ    = 20;
constexpr int GBATCH = 16;   // batches per block (256 thr / 16-lane rows)
constexpr int BSTR  = 151;   // float4 per batch in staging (60+60+30+1 pad)
constexpr int PRIO  = 60;
constexpr int TRKO  = 120;

typedef float v4f __attribute__((ext_vector_type(4)));

struct Aff { float R[9]; float p[3]; };

__device__ __forceinline__ void rpy2r_dev(float r, float p, float y, float R[9]) {
    float sr, cr, sp, cp, sy, cy;
    __sincosf(r, &sr, &cr);
    __sincosf(p, &sp, &cp);
    __sincosf(y, &sy, &cy);
    R[0] = cy * cp; R[1] = cy * sp * sr - sy * cr; R[2] = cy * sp * cr + sy * sr;
    R[3] = sy * cp; R[4] = sy * sp * sr + cy * cr; R[5] = sy * sp * cr - cy * sr;
    R[6] = -sp;     R[7] = cp * sr;                R[8] = cp * cr;
}

__device__ __forceinline__ void mat33_mul(const float A[9], const float B[9], float C[9]) {
#pragma unroll
    for (int i = 0; i < 3; ++i) {
        C[3 * i + 0] = A[3 * i + 0] * B[0] + A[3 * i + 1] * B[3] + A[3 * i + 2] * B[6];
        C[3 * i + 1] = A[3 * i + 0] * B[1] + A[3 * i + 1] * B[4] + A[3 * i + 2] * B[7];
        C[3 * i + 2] = A[3 * i + 0] * B[2] + A[3 * i + 1] * B[5] + A[3 * i + 2] * B[8];
    }
}

__device__ __forceinline__ Aff compose(const Aff& A, const Aff& B) {
    Aff C;
    mat33_mul(A.R, B.R, C.R);
#pragma unroll
    for (int i = 0; i < 3; ++i)
        C.p[i] = fmaf(A.R[3 * i + 0], B.p[0],
                 fmaf(A.R[3 * i + 1], B.p[1],
                 fmaf(A.R[3 * i + 2], B.p[2], A.p[i])));
    return C;
}

// row_shr:D within 16-lane row via DPP (pure VALU, no LDS pipe).
template <int D>
__device__ __forceinline__ float dpp_shr(float x) {
    constexpr int CTRL = 0x110 | D;   // row_shr:D
    return __int_as_float(__builtin_amdgcn_update_dpp(
        0, __float_as_int(x), CTRL, 0xF, 0xF, true));
}

template <int D>
__device__ __forceinline__ Aff dpp_up(const Aff& V) {
    Aff N;
#pragma unroll
    for (int k = 0; k < 9; ++k) N.R[k] = dpp_shr<D>(V.R[k]);
#pragma unroll
    for (int k = 0; k < 3; ++k) N.p[k] = dpp_shr<D>(V.p[k]);
    return N;
}

// Local step for joint j: S = revstep @ pristep, revstep = rev_T_off@rodrigues(q)
__device__ __forceinline__ void joint_step(const float4 cst[11], float rq, float pq,
                                           Aff& revstep, Aff& S) {
    float s, c;
    __sincosf(rq, &s, &c);
    const float4 a4 = cst[9];
    const float ax = a4.x, ay = a4.y, az = a4.z, omc = 1.0f - c;
    float Rr[9];
    Rr[0] = c + omc * ax * ax;      Rr[1] = omc * ax * ay - s * az; Rr[2] = omc * ax * az + s * ay;
    Rr[3] = omc * ax * ay + s * az; Rr[4] = c + omc * ay * ay;      Rr[5] = omc * ay * az - s * ax;
    Rr[6] = omc * ax * az - s * ay; Rr[7] = omc * ay * az + s * ax; Rr[8] = c + omc * az * az;

    const float4 cr0 = cst[0], cr1 = cst[1], cr2 = cst[2];
    const float Roff[9] = {cr0.x, cr0.y, cr0.z, cr1.x, cr1.y, cr1.z, cr2.x, cr2.y, cr2.z};
    mat33_mul(Roff, Rr, revstep.R);
    revstep.p[0] = cr0.w; revstep.p[1] = cr1.w; revstep.p[2] = cr2.w;

    const float4 cp0 = cst[3], cp1 = cst[4], cp2 = cst[5];
    const float4 w4 = cst[10];
    const float Rpoff[9] = {cp0.x, cp0.y, cp0.z, cp1.x, cp1.y, cp1.z, cp2.x, cp2.y, cp2.z};
    const float pp[3] = {fmaf(pq, w4.x, cp0.w), fmaf(pq, w4.y, cp1.w), fmaf(pq, w4.z, cp2.w)};
    mat33_mul(revstep.R, Rpoff, S.R);
#pragma unroll
    for (int i = 0; i < 3; ++i)
        S.p[i] = fmaf(revstep.R[3 * i + 0], pp[0],
                 fmaf(revstep.R[3 * i + 1], pp[1],
                 fmaf(revstep.R[3 * i + 2], pp[2], revstep.p[i])));
}

__device__ __forceinline__ void stage3(v4f* sg, int base, const Aff& A) {
    sg[base + 0] = (v4f){A.R[0], A.R[1], A.R[2], A.p[0]};
    sg[base + 1] = (v4f){A.R[3], A.R[4], A.R[5], A.p[1]};
    sg[base + 2] = (v4f){A.R[6], A.R[7], A.R[8], A.p[2]};
}

// cst layout per joint (11 float4):
//  [0..2] rev_T_off rows (p in .w)  [3..5] pri_T_off rows (p in .w)
//  [6..8] T_track rows (p in .w)    [9] unit rev axis      [10] R_pri_off@pri_axis
__global__ __launch_bounds__(256) void fk_kernel(
    const float* __restrict__ rev_q,      const float* __restrict__ pri_q,
    const float* __restrict__ rev_p_off,  const float* __restrict__ rev_rpy_off,
    const float* __restrict__ pri_p_off,  const float* __restrict__ pri_rpy_off,
    const float* __restrict__ rev_axis,   const float* __restrict__ pri_axis,
    const float* __restrict__ p_track,    const float* __restrict__ rpy_track,
    float* __restrict__ out, int B)
{
    __shared__ float4 cst[NJ][11];
    __shared__ v4f stg[GBATCH * BSTR];   // 38,656 B staging
    const int t = threadIdx.x;

    if (t < NJ) {
        const int j = t;
        float Ro[9], Rp[9], Rt[9];
        rpy2r_dev(rev_rpy_off[3 * j], rev_rpy_off[3 * j + 1], rev_rpy_off[3 * j + 2], Ro);
        rpy2r_dev(pri_rpy_off[3 * j], pri_rpy_off[3 * j + 1], pri_rpy_off[3 * j + 2], Rp);
        rpy2r_dev(rpy_track[3 * j],   rpy_track[3 * j + 1],   rpy_track[3 * j + 2],   Rt);
        cst[j][0] = make_float4(Ro[0], Ro[1], Ro[2], rev_p_off[3 * j + 0]);
        cst[j][1] = make_float4(Ro[3], Ro[4], Ro[5], rev_p_off[3 * j + 1]);
        cst[j][2] = make_float4(Ro[6], Ro[7], Ro[8], rev_p_off[3 * j + 2]);
        cst[j][3] = make_float4(Rp[0], Rp[1], Rp[2], pri_p_off[3 * j + 0]);
        cst[j][4] = make_float4(Rp[3], Rp[4], Rp[5], pri_p_off[3 * j + 1]);
        cst[j][5] = make_float4(Rp[6], Rp[7], Rp[8], pri_p_off[3 * j + 2]);
        cst[j][6] = make_float4(Rt[0], Rt[1], Rt[2], p_track[3 * j + 0]);
        cst[j][7] = make_float4(Rt[3], Rt[4], Rt[5], p_track[3 * j + 1]);
        cst[j][8] = make_float4(Rt[6], Rt[7], Rt[8], p_track[3 * j + 2]);
        const float ax = rev_axis[3 * j], ay = rev_axis[3 * j + 1], az = rev_axis[3 * j + 2];
        const float inv = 1.0f / (sqrtf(ax * ax + ay * ay + az * az) + 1e-12f);
        cst[j][9] = make_float4(ax * inv, ay * inv, az * inv, 0.0f);
        const float px = pri_axis[3 * j], py = pri_axis[3 * j + 1], pz = pri_axis[3 * j + 2];
        cst[j][10] = make_float4(Rp[0] * px + Rp[1] * py + Rp[2] * pz,
                                 Rp[3] * px + Rp[4] * py + Rp[5] * pz,
                                 Rp[6] * px + Rp[7] * py + Rp[8] * pz, 0.0f);
    }
    __syncthreads();

    const int l = t & 15;               // lane in 16-lane row; owns joints 2l, 2l+1
    const int g = t >> 4;               // batch slot within block (0..15)
    const int b = blockIdx.x * GBATCH + g;

    if (l < 10) {
        const int j0 = 2 * l, j1 = 2 * l + 1;
        const float rq0 = rev_q[(size_t)b * NJ + j0];
        const float rq1 = rev_q[(size_t)b * NJ + j1];
        const float pq0 = pri_q[(size_t)b * NJ + j0];
        const float pq1 = pri_q[(size_t)b * NJ + j1];

        Aff rs0, S0, rs1, S1;
        joint_step(cst[j0], rq0, pq0, rs0, S0);
        joint_step(cst[j1], rq1, pq1, rs1, S1);

        Aff V = compose(S0, S1);        // Q_l

        // Kogge-Stone inclusive scan over 10 lanes (intra-row DPP shifts)
        { Aff N = dpp_up<1>(V); if (l >= 1) V = compose(N, V); }
        { Aff N = dpp_up<2>(V); if (l >= 2) V = compose(N, V); }
        { Aff N = dpp_up<4>(V); if (l >= 4) V = compose(N, V); }
        { Aff N = dpp_up<8>(V); if (l >= 8) V = compose(N, V); }

        Aff E = dpp_up<1>(V);           // exclusive prefix = T_{2l-1}
        if (l == 0) {
            E.R[0] = 1.f; E.R[1] = 0.f; E.R[2] = 0.f;
            E.R[3] = 0.f; E.R[4] = 1.f; E.R[5] = 0.f;
            E.R[6] = 0.f; E.R[7] = 0.f; E.R[8] = 1.f;
            E.p[0] = 0.f; E.p[1] = 0.f; E.p[2] = 0.f;
        }

        const Aff rev0 = compose(E, rs0);
        const Aff T0   = compose(E, S0);     // = pri0
        const Aff rev1 = compose(T0, rs1);
        // pri1 = V

        v4f* sg = &stg[g * BSTR];
        stage3(sg, 3 * j0, rev0);
        stage3(sg, 3 * j1, rev1);
        stage3(sg, PRIO + 3 * j0, T0);
        stage3(sg, PRIO + 3 * j1, V);

        // track frames at even joints (j0 = 2l), slot l
        {
            const float4 ct0 = cst[j0][6], ct1 = cst[j0][7], ct2 = cst[j0][8];
            Aff Tt;
            Tt.R[0] = ct0.x; Tt.R[1] = ct0.y; Tt.R[2] = ct0.z;
            Tt.R[3] = ct1.x; Tt.R[4] = ct1.y; Tt.R[5] = ct1.z;
            Tt.R[6] = ct2.x; Tt.R[7] = ct2.y; Tt.R[8] = ct2.z;
            Tt.p[0] = ct0.w; Tt.p[1] = ct1.w; Tt.p[2] = ct2.w;
            const Aff Trk = compose(T0, Tt);
            stage3(sg, TRKO + 3 * l, Trk);
        }
    }

    // --- per-wave coalesced copy: wave w owns batches 4w..4w+3 (contiguous).
    // Same-wave LDS write->read: ordered by hardware (lgkmcnt), no barrier.
    v4f* out4 = reinterpret_cast<v4f*>(out);
    const v4f bot = (v4f){0.f, 0.f, 0.f, 1.f};
    const int w = t >> 6, lw = t & 63;
    const int gbase = 4 * w;
    const size_t batch0 = (size_t)blockIdx.x * GBATCH + gbase;

    // Tracking: 4*40 = 160 f4 at out4[batch0*40]
    {
        v4f* dst = out4 + batch0 * 40;
#pragma unroll
        for (int k = lw; k < 160; k += 64) {
            const int gg = k / 40, ww = k - gg * 40;
            const int jt = ww >> 2, r = ww & 3;
            const v4f v = (r == 3) ? bot : stg[(gbase + gg) * BSTR + TRKO + 3 * jt + r];
            __builtin_nontemporal_store(v, &dst[k]);
        }
    }
    // Rev: 4*80 = 320 f4 at out4[B*40 + batch0*80]
    {
        v4f* dst = out4 + (size_t)B * 40 + batch0 * 80;
#pragma unroll
        for (int k = lw; k < 320; k += 64) {
            const int gg = k / 80, ww = k - gg * 80;
            const int jj = ww >> 2, r = ww & 3;
            const v4f v = (r == 3) ? bot : stg[(gbase + gg) * BSTR + 3 * jj + r];
            __builtin_nontemporal_store(v, &dst[k]);
        }
    }
    // Pri: 4*80 = 320 f4 at out4[B*120 + batch0*80]
    {
        v4f* dst = out4 + (size_t)B * 120 + batch0 * 80;
#pragma unroll
        for (int k = lw; k < 320; k += 64) {
            const int gg = k / 80, ww = k - gg * 80;
            const int jj = ww >> 2, r = ww & 3;
            const v4f v = (r == 3) ? bot : stg[(gbase + gg) * BSTR + PRIO + 3 * jj + r];
            __builtin_nontemporal_store(v, &dst[k]);
        }
    }
}

extern "C" void kernel_launch(void* const* d_in, const int* in_sizes, int n_in,
                              void* d_out, int out_size, void* d_ws, size_t ws_size,
                              hipStream_t stream) {
    (void)n_in; (void)out_size; (void)d_ws; (void)ws_size;
    const float* rev_q       = (const float*)d_in[0];
    const float* pri_q       = (const float*)d_in[1];
    const float* rev_p_off   = (const float*)d_in[2];
    const float* rev_rpy_off = (const float*)d_in[3];
    const float* pri_p_off   = (const float*)d_in[4];
    const float* pri_rpy_off = (const float*)d_in[5];
    const float* rev_axis    = (const float*)d_in[6];
    const float* pri_axis    = (const float*)d_in[7];
    const float* p_track     = (const float*)d_in[8];
    const float* rpy_track   = (const float*)d_in[9];

    const int B = in_sizes[0] / NJ;              // 32768 (multiple of GBATCH)
    const int blocks = B / GBATCH;               // 2048
    fk_kernel<<<dim3(blocks), dim3(256), 0, stream>>>(
        rev_q, pri_q, rev_p_off, rev_rpy_off, pri_p_off, pri_rpy_off,
        rev_axis, pri_axis, p_track, rpy_track, (float*)d_out, B);
}

// Round 8
// 136.446 us; speedup vs baseline: 1.3541x; 1.3541x over previous
//
#include <hip/hip_runtime.h>
#include <math.h>

// Forward kinematics chain: B=32768 batches, J=20 joints.
// out = concat(TrackingSE3 (B,10,4,4), RevSE3 (B,20,4,4), PriSE3 (B,20,4,4)) fp32.
//
// v5 = v3b (measured best, ~37us kernel) with ONE change: plain stores instead
// of __builtin_nontemporal_store. Harness fills reach 6.3 TB/s with plain
// stores; nt (no-allocate) bypasses L2 write-combining and is the prime
// suspect for the ~3 TB/s effective ceiling + v4's write/fetch amplification
// (RMW signature). Single-variable experiment vs the measured-best baseline.
// (Round 7 resubmission: prior round hit GPUAcquisitionTimeout, never ran.)

constexpr int NJ  = 20;
constexpr int GB  = 8;     // batches per block (256 threads / 32-lane groups)
constexpr int BSTR = 151;  // float4 per batch in staging (60 rev + 60 pri + 30 trk + 1 pad)
constexpr int PRIO = 60;
constexpr int TRKO = 120;

typedef float v4f __attribute__((ext_vector_type(4)));

struct Aff { float R[9]; float p[3]; };

__device__ __forceinline__ void rpy2r_dev(float r, float p, float y, float R[9]) {
    float sr, cr, sp, cp, sy, cy;
    __sincosf(r, &sr, &cr);
    __sincosf(p, &sp, &cp);
    __sincosf(y, &sy, &cy);
    R[0] = cy * cp; R[1] = cy * sp * sr - sy * cr; R[2] = cy * sp * cr + sy * sr;
    R[3] = sy * cp; R[4] = sy * sp * sr + cy * cr; R[5] = sy * sp * cr - cy * sr;
    R[6] = -sp;     R[7] = cp * sr;                R[8] = cp * cr;
}

__device__ __forceinline__ void mat33_mul(const float A[9], const float B[9], float C[9]) {
#pragma unroll
    for (int i = 0; i < 3; ++i) {
        C[3 * i + 0] = A[3 * i + 0] * B[0] + A[3 * i + 1] * B[3] + A[3 * i + 2] * B[6];
        C[3 * i + 1] = A[3 * i + 0] * B[1] + A[3 * i + 1] * B[4] + A[3 * i + 2] * B[7];
        C[3 * i + 2] = A[3 * i + 0] * B[2] + A[3 * i + 1] * B[5] + A[3 * i + 2] * B[8];
    }
}

__device__ __forceinline__ Aff compose(const Aff& A, const Aff& B) {
    Aff C;
    mat33_mul(A.R, B.R, C.R);
#pragma unroll
    for (int i = 0; i < 3; ++i)
        C.p[i] = fmaf(A.R[3 * i + 0], B.p[0],
                 fmaf(A.R[3 * i + 1], B.p[1],
                 fmaf(A.R[3 * i + 2], B.p[2], A.p[i])));
    return C;
}

__device__ __forceinline__ Aff shfl_up_aff(const Aff& V, int d) {
    Aff N;
#pragma unroll
    for (int k = 0; k < 9; ++k) N.R[k] = __shfl_up(V.R[k], d, 32);
#pragma unroll
    for (int k = 0; k < 3; ++k) N.p[k] = __shfl_up(V.p[k], d, 32);
    return N;
}

// cst layout per joint (11 float4):
//  [0..2] rev_T_off rows (p in .w)  [3..5] pri_T_off rows (p in .w)
//  [6..8] T_track rows (p in .w)    [9] unit rev axis      [10] R_pri_off@pri_axis
__global__ __launch_bounds__(256) void fk_kernel(
    const float* __restrict__ rev_q,      const float* __restrict__ pri_q,
    const float* __restrict__ rev_p_off,  const float* __restrict__ rev_rpy_off,
    const float* __restrict__ pri_p_off,  const float* __restrict__ pri_rpy_off,
    const float* __restrict__ rev_axis,   const float* __restrict__ pri_axis,
    const float* __restrict__ p_track,    const float* __restrict__ rpy_track,
    float* __restrict__ out, int B)
{
    __shared__ float4 cst[NJ][11];
    __shared__ v4f stg[GB * BSTR];   // 19,328 B staging
    const int t = threadIdx.x;

    if (t < NJ) {
        const int j = t;
        float Ro[9], Rp[9], Rt[9];
        rpy2r_dev(rev_rpy_off[3 * j], rev_rpy_off[3 * j + 1], rev_rpy_off[3 * j + 2], Ro);
        rpy2r_dev(pri_rpy_off[3 * j], pri_rpy_off[3 * j + 1], pri_rpy_off[3 * j + 2], Rp);
        rpy2r_dev(rpy_track[3 * j],   rpy_track[3 * j + 1],   rpy_track[3 * j + 2],   Rt);
        cst[j][0] = make_float4(Ro[0], Ro[1], Ro[2], rev_p_off[3 * j + 0]);
        cst[j][1] = make_float4(Ro[3], Ro[4], Ro[5], rev_p_off[3 * j + 1]);
        cst[j][2] = make_float4(Ro[6], Ro[7], Ro[8], rev_p_off[3 * j + 2]);
        cst[j][3] = make_float4(Rp[0], Rp[1], Rp[2], pri_p_off[3 * j + 0]);
        cst[j][4] = make_float4(Rp[3], Rp[4], Rp[5], pri_p_off[3 * j + 1]);
        cst[j][5] = make_float4(Rp[6], Rp[7], Rp[8], pri_p_off[3 * j + 2]);
        cst[j][6] = make_float4(Rt[0], Rt[1], Rt[2], p_track[3 * j + 0]);
        cst[j][7] = make_float4(Rt[3], Rt[4], Rt[5], p_track[3 * j + 1]);
        cst[j][8] = make_float4(Rt[6], Rt[7], Rt[8], p_track[3 * j + 2]);
        const float ax = rev_axis[3 * j], ay = rev_axis[3 * j + 1], az = rev_axis[3 * j + 2];
        const float inv = 1.0f / (sqrtf(ax * ax + ay * ay + az * az) + 1e-12f);
        cst[j][9] = make_float4(ax * inv, ay * inv, az * inv, 0.0f);
        const float px = pri_axis[3 * j], py = pri_axis[3 * j + 1], pz = pri_axis[3 * j + 2];
        cst[j][10] = make_float4(Rp[0] * px + Rp[1] * py + Rp[2] * pz,
                                 Rp[3] * px + Rp[4] * py + Rp[5] * pz,
                                 Rp[6] * px + Rp[7] * py + Rp[8] * pz, 0.0f);
    }
    __syncthreads();

    const int j = t & 31;               // joint lane within width-32 group
    const int g = t >> 5;               // batch slot within block
    const int b = blockIdx.x * GB + g;  // B is a multiple of GB

    if (j < NJ) {
        const float rq = rev_q[(size_t)b * NJ + j];
        const float pq = pri_q[(size_t)b * NJ + j];

        // --- per-joint local step ---
        float s, c;
        __sincosf(rq, &s, &c);
        const float4 a4 = cst[j][9];
        const float ax = a4.x, ay = a4.y, az = a4.z, omc = 1.0f - c;
        float Rr[9];
        Rr[0] = c + omc * ax * ax;      Rr[1] = omc * ax * ay - s * az; Rr[2] = omc * ax * az + s * ay;
        Rr[3] = omc * ax * ay + s * az; Rr[4] = c + omc * ay * ay;      Rr[5] = omc * ay * az - s * ax;
        Rr[6] = omc * ax * az - s * ay; Rr[7] = omc * ay * az + s * ax; Rr[8] = c + omc * az * az;

        const float4 cr0 = cst[j][0], cr1 = cst[j][1], cr2 = cst[j][2];
        const float Roff[9] = {cr0.x, cr0.y, cr0.z, cr1.x, cr1.y, cr1.z, cr2.x, cr2.y, cr2.z};
        Aff revstep;                    // rev_T_off @ rodrigues(q)
        mat33_mul(Roff, Rr, revstep.R);
        revstep.p[0] = cr0.w; revstep.p[1] = cr1.w; revstep.p[2] = cr2.w;

        const float4 cp0 = cst[j][3], cp1 = cst[j][4], cp2 = cst[j][5];
        const float4 w4 = cst[j][10];
        const float Rpoff[9] = {cp0.x, cp0.y, cp0.z, cp1.x, cp1.y, cp1.z, cp2.x, cp2.y, cp2.z};
        const float pp[3] = {fmaf(pq, w4.x, cp0.w), fmaf(pq, w4.y, cp1.w), fmaf(pq, w4.z, cp2.w)};

        Aff V;                          // S_j = revstep @ pristep
        mat33_mul(revstep.R, Rpoff, V.R);
#pragma unroll
        for (int i = 0; i < 3; ++i)
            V.p[i] = fmaf(revstep.R[3 * i + 0], pp[0],
                     fmaf(revstep.R[3 * i + 1], pp[1],
                     fmaf(revstep.R[3 * i + 2], pp[2], revstep.p[i])));

        // --- Kogge-Stone inclusive scan: V_j = S_0 @ ... @ S_j ---
#pragma unroll
        for (int d = 1; d < 32; d <<= 1) {
            Aff N = shfl_up_aff(V, d);
            if (j >= d) V = compose(N, V);
        }

        // --- RevSE3_j = V_{j-1} @ revstep_j  (V_{-1} = I) ---
        Aff P = shfl_up_aff(V, 1);
        if (j == 0) {
            P.R[0] = 1.f; P.R[1] = 0.f; P.R[2] = 0.f;
            P.R[3] = 0.f; P.R[4] = 1.f; P.R[5] = 0.f;
            P.R[6] = 0.f; P.R[7] = 0.f; P.R[8] = 1.f;
            P.p[0] = 0.f; P.p[1] = 0.f; P.p[2] = 0.f;
        }
        const Aff Rev = compose(P, revstep);

        // --- stage rows 0..2 into LDS ---
        v4f* sg = &stg[g * BSTR];
        sg[3 * j + 0] = (v4f){Rev.R[0], Rev.R[1], Rev.R[2], Rev.p[0]};
        sg[3 * j + 1] = (v4f){Rev.R[3], Rev.R[4], Rev.R[5], Rev.p[1]};
        sg[3 * j + 2] = (v4f){Rev.R[6], Rev.R[7], Rev.R[8], Rev.p[2]};
        sg[PRIO + 3 * j + 0] = (v4f){V.R[0], V.R[1], V.R[2], V.p[0]};
        sg[PRIO + 3 * j + 1] = (v4f){V.R[3], V.R[4], V.R[5], V.p[1]};
        sg[PRIO + 3 * j + 2] = (v4f){V.R[6], V.R[7], V.R[8], V.p[2]};

        if ((j & 1) == 0) {
            const float4 ct0 = cst[j][6], ct1 = cst[j][7], ct2 = cst[j][8];
            Aff T;
            T.R[0] = ct0.x; T.R[1] = ct0.y; T.R[2] = ct0.z;
            T.R[3] = ct1.x; T.R[4] = ct1.y; T.R[5] = ct1.z;
            T.R[6] = ct2.x; T.R[7] = ct2.y; T.R[8] = ct2.z;
            T.p[0] = ct0.w; T.p[1] = ct1.w; T.p[2] = ct2.w;
            const Aff Trk = compose(V, T);
            const int jt = j >> 1;
            sg[TRKO + 3 * jt + 0] = (v4f){Trk.R[0], Trk.R[1], Trk.R[2], Trk.p[0]};
            sg[TRKO + 3 * jt + 1] = (v4f){Trk.R[3], Trk.R[4], Trk.R[5], Trk.p[1]};
            sg[TRKO + 3 * jt + 2] = (v4f){Trk.R[6], Trk.R[7], Trk.R[8], Trk.p[2]};
        }
    }
    __syncthreads();

    // --- cooperative, fully-coalesced copy: lane-contiguous float4 stores ---
    v4f* out4 = reinterpret_cast<v4f*>(out);
    const v4f bot = (v4f){0.f, 0.f, 0.f, 1.f};
    const int blockBase = blockIdx.x * GB;

    // Tracking span: GB*40 = 320 float4 at out4[blockBase*40]
    {
        v4f* dst = out4 + (size_t)blockBase * 40;
#pragma unroll
        for (int k = t; k < GB * 40; k += 256) {
            const int gg = k / 40, w = k - gg * 40;
            const int jt = w >> 2, r = w & 3;
            dst[k] = (r == 3) ? bot : stg[gg * BSTR + TRKO + 3 * jt + r];
        }
    }
    // Rev span: GB*80 = 640 float4 at out4[B*40 + blockBase*80]
    {
        v4f* dst = out4 + (size_t)B * 40 + (size_t)blockBase * 80;
#pragma unroll
        for (int k = t; k < GB * 80; k += 256) {
            const int gg = k / 80, w = k - gg * 80;
            const int jj = w >> 2, r = w & 3;
            dst[k] = (r == 3) ? bot : stg[gg * BSTR + 3 * jj + r];
        }
    }
    // Pri span: GB*80 = 640 float4 at out4[B*120 + blockBase*80]
    {
        v4f* dst = out4 + (size_t)B * 120 + (size_t)blockBase * 80;
#pragma unroll
        for (int k = t; k < GB * 80; k += 256) {
            const int gg = k / 80, w = k - gg * 80;
            const int jj = w >> 2, r = w & 3;
            dst[k] = (r == 3) ? bot : stg[gg * BSTR + PRIO + 3 * jj + r];
        }
    }
}

extern "C" void kernel_launch(void* const* d_in, const int* in_sizes, int n_in,
                              void* d_out, int out_size, void* d_ws, size_t ws_size,
                              hipStream_t stream) {
    (void)n_in; (void)out_size; (void)d_ws; (void)ws_size;
    const float* rev_q       = (const float*)d_in[0];
    const float* pri_q       = (const float*)d_in[1];
    const float* rev_p_off   = (const float*)d_in[2];
    const float* rev_rpy_off = (const float*)d_in[3];
    const float* pri_p_off   = (const float*)d_in[4];
    const float* pri_rpy_off = (const float*)d_in[5];
    const float* rev_axis    = (const float*)d_in[6];
    const float* pri_axis    = (const float*)d_in[7];
    const float* p_track     = (const float*)d_in[8];
    const float* rpy_track   = (const float*)d_in[9];

    const int B = in_sizes[0] / NJ;              // 32768 (multiple of GB)
    const int blocks = B / GB;                   // 4096
    fk_kernel<<<dim3(blocks), dim3(256), 0, stream>>>(
        rev_q, pri_q, rev_p_off, rev_rpy_off, pri_p_off, pri_rpy_off,
        rev_axis, pri_axis, p_track, rpy_track, (float*)d_out, B);
}